// Round 1
// baseline (449.985 us; speedup 1.0000x reference)
//
#include <hip/hip_runtime.h>

#define NCP   64
#define BTS   16
#define NTPL  2048
#define TSTEPS 6
#define NFLOW  7           // T+1 stored (p,q) states
#define DTF   0.2f         // 1/(T-1)

// ---------- fast scalar helpers ----------
__device__ __forceinline__ float fast_rcp(float x) {
    return __builtin_amdgcn_rcpf(x);
}
__device__ __forceinline__ float fast_tanh(float x) {
    // tanh(x) = 1 - 2/(1+exp(2x)); exact limits at +/-inf, ~1e-7 rel error
    float e = __expf(2.0f * x);
    return 1.0f - 2.0f * fast_rcp(1.0f + e);
}

// ---------- tiny MLP forward: z(4) -> h1(10) -> h2(10) -> o(3) ----------
// W1:[4,10] W2:[10,10] W3:[10,3], row-major (out_k = sum_c z_c * W[c,k])
template <bool STASH>
__device__ __forceinline__ void mlp_fwd(
    float z0, float z1, float z2, float z3,
    const float* __restrict__ W1, const float* __restrict__ b1,
    const float* __restrict__ W2, const float* __restrict__ b2,
    const float* __restrict__ W3, const float* __restrict__ b3,
    float& o0, float& e1, float& e2, float* h1s, float* h2s)
{
    float h1[10];
#pragma unroll
    for (int k = 0; k < 10; ++k) {
        float u = fmaf(z3, W1[30 + k],
                  fmaf(z2, W1[20 + k],
                  fmaf(z1, W1[10 + k],
                  fmaf(z0, W1[k], b1[k]))));
        h1[k] = fast_tanh(u);
        if (STASH) h1s[k] = h1[k];
    }
    float u2[10];
#pragma unroll
    for (int k = 0; k < 10; ++k) u2[k] = b2[k];
#pragma unroll
    for (int c = 0; c < 10; ++c) {
#pragma unroll
        for (int k = 0; k < 10; ++k) u2[k] = fmaf(h1[c], W2[c * 10 + k], u2[k]);
    }
    float o0a = b3[0], o1a = b3[1], o2a = b3[2];
#pragma unroll
    for (int c = 0; c < 10; ++c) {
        float h2 = fast_tanh(u2[c]);
        if (STASH) h2s[c] = h2;
        o0a = fmaf(h2, W3[c * 3 + 0], o0a);
        o1a = fmaf(h2, W3[c * 3 + 1], o1a);
        o2a = fmaf(h2, W3[c * 3 + 2], o2a);
    }
    o0 = o0a;
    e1 = __expf(o1a);
    e2 = __expf(o2a);
}

// ---------- init: p_hist[0] = broadcast(control_points), q_hist[0] = q_0 ----------
__global__ void init_kernel(const float* __restrict__ q0,
                            const float* __restrict__ cp,
                            float* __restrict__ p_hist,
                            float* __restrict__ q_hist)
{
    int t = blockIdx.x * blockDim.x + threadIdx.x;   // over BTS*NCP = 1024 point slots
    if (t < BTS * NCP) {
        int j = t & (NCP - 1);
        p_hist[t * 2 + 0] = cp[j * 2 + 0];
        p_hist[t * 2 + 1] = cp[j * 2 + 1];
        q_hist[t * 2 + 0] = q0[t * 2 + 0];
        q_hist[t * 2 + 1] = q0[t * 2 + 1];
    }
}

// ---------- one symplectic-Euler shooting step ----------
// block = (batch, a); thread = b. Each thread does 2 MLP fwd+bwd evals, then
// wave-reduce (dh_dq_a, dH/dp_a) over the 64 b's. 1 wave per block.
__global__ __launch_bounds__(64)
void shoot_step(const float* __restrict__ p_in, const float* __restrict__ q_in,
                float* __restrict__ p_out, float* __restrict__ q_out,
                const float* __restrict__ W1, const float* __restrict__ b1,
                const float* __restrict__ W2, const float* __restrict__ b2,
                const float* __restrict__ W3, const float* __restrict__ b3)
{
    int blk = blockIdx.x;          // 0..BTS*NCP-1
    int batch = blk >> 6;
    int a = blk & (NCP - 1);
    int b = threadIdx.x;

    const float* pB = p_in + batch * NCP * 2;
    const float* qB = q_in + batch * NCP * 2;
    float pax = pB[a * 2 + 0], pay = pB[a * 2 + 1];
    float qax = qB[a * 2 + 0], qay = qB[a * 2 + 1];
    float pbx = pB[b * 2 + 0], pby = pB[b * 2 + 1];
    float qbx = qB[b * 2 + 0], qby = qB[b * 2 + 1];

    float dhq_x = 0.f, dhq_y = 0.f;   // (K q)_a accumulator
    float g_x = 0.f, g_y = 0.f;       // dH/dp_a accumulator

    // cross term of dw/do_0 is identical for both evals
    float cross = fmaf(qax, qby, qay * qbx);

#pragma unroll
    for (int e = 0; e < 2; ++e) {
        // eval 0: z=[p_a,p_b] -> take dz[0:2]; eval 1: z=[p_b,p_a] -> take dz[2:4]
        float z0 = e ? pbx : pax;
        float z1 = e ? pby : pay;
        float z2 = e ? pax : pbx;
        float z3 = e ? pay : pby;

        float h1[10], h2[10];
        float o0, e1, e2;
        mlp_fwd<true>(z0, z1, z2, z3, W1, b1, W2, b2, W3, b3, o0, e1, e2, h1, h2);

        // dh_dq_a += 0.5 * S * q_b   (S = [[e1,o0],[o0,e2]])
        dhq_x = fmaf(0.5f, fmaf(e1, qbx, o0 * qby), dhq_x);
        dhq_y = fmaf(0.5f, fmaf(o0, qbx, e2 * qby), dhq_y);

        // dw/do for w = qa^T S qb (same formula both evals)
        float d0 = cross;
        float d1 = e1 * qax * qbx;
        float d2 = e2 * qay * qby;

        // backward through MLP
        float du2[10];
#pragma unroll
        for (int c = 0; c < 10; ++c) {
            float dh2 = fmaf(W3[c * 3 + 0], d0,
                        fmaf(W3[c * 3 + 1], d1, W3[c * 3 + 2] * d2));
            du2[c] = dh2 * (1.0f - h2[c] * h2[c]);
        }
        float du1[10];
#pragma unroll
        for (int c = 0; c < 10; ++c) {
            float dh1 = 0.f;
#pragma unroll
            for (int k = 0; k < 10; ++k) dh1 = fmaf(W2[c * 10 + k], du2[k], dh1);
            du1[c] = dh1 * (1.0f - h1[c] * h1[c]);
        }
        // only need 2 of the 4 z-gradients per eval
        int c0 = e ? 2 : 0;
        float ga = 0.f, gb = 0.f;
#pragma unroll
        for (int k = 0; k < 10; ++k) {
            ga = fmaf(W1[(0 + c0) * 10 + k], du1[k], ga);
            gb = fmaf(W1[(1 + c0) * 10 + k], du1[k], gb);
        }
        g_x = fmaf(0.5f, ga, g_x);
        g_y = fmaf(0.5f, gb, g_y);
    }

    // wave butterfly reduction over the 64 lanes
#pragma unroll
    for (int off = 32; off > 0; off >>= 1) {
        dhq_x += __shfl_xor(dhq_x, off);
        dhq_y += __shfl_xor(dhq_y, off);
        g_x   += __shfl_xor(g_x, off);
        g_y   += __shfl_xor(g_y, off);
    }

    if (b == 0) {
        float* pO = p_out + (batch * NCP + a) * 2;
        float* qO = q_out + (batch * NCP + a) * 2;
        pO[0] = fmaf(DTF, dhq_x, pax);
        pO[1] = fmaf(DTF, dhq_y, pay);
        qO[0] = fmaf(-DTF, g_x, qax);
        qO[1] = fmaf(-DTF, g_y, qay);
    }
}

// ---------- flow the template points through the 7 stored (p,q) states ----------
// block = (batch, template point i); thread = control point j. One wave/block.
__global__ __launch_bounds__(64)
void flow_kernel(const float* __restrict__ tpl,
                 const float* __restrict__ p_hist,   // [NFLOW][BTS][NCP][2]
                 const float* __restrict__ q_hist,
                 float* __restrict__ out,            // [BTS][NTPL][2]
                 const float* __restrict__ W1, const float* __restrict__ b1,
                 const float* __restrict__ W2, const float* __restrict__ b2,
                 const float* __restrict__ W3, const float* __restrict__ b3)
{
    int blk = blockIdx.x;              // 0..BTS*NTPL-1
    int batch = blk >> 11;             // / NTPL
    int i = blk & (NTPL - 1);
    int j = threadIdx.x;

    float x0 = tpl[i * 2 + 0];
    float x1 = tpl[i * 2 + 1];

#pragma unroll
    for (int s = 0; s < NFLOW; ++s) {
        const float* p = p_hist + (((size_t)s * BTS + batch) * NCP + j) * 2;
        const float* q = q_hist + (((size_t)s * BTS + batch) * NCP + j) * 2;
        float pj0 = p[0], pj1 = p[1];
        float qj0 = q[0], qj1 = q[1];

        float vx = 0.f, vy = 0.f;
#pragma unroll
        for (int e = 0; e < 2; ++e) {
            float z0 = e ? pj0 : x0;
            float z1 = e ? pj1 : x1;
            float z2 = e ? x0 : pj0;
            float z3 = e ? x1 : pj1;
            float o0, e1, e2;
            mlp_fwd<false>(z0, z1, z2, z3, W1, b1, W2, b2, W3, b3,
                           o0, e1, e2, nullptr, nullptr);
            vx = fmaf(0.5f, fmaf(e1, qj0, o0 * qj1), vx);
            vy = fmaf(0.5f, fmaf(o0, qj0, e2 * qj1), vy);
        }
        // butterfly: all lanes end with the full sum -> update x uniformly
#pragma unroll
        for (int off = 32; off > 0; off >>= 1) {
            vx += __shfl_xor(vx, off);
            vy += __shfl_xor(vy, off);
        }
        x0 = fmaf(DTF, vx, x0);
        x1 = fmaf(DTF, vy, x1);
    }

    if (j == 0) {
        out[((size_t)batch * NTPL + i) * 2 + 0] = x0;
        out[((size_t)batch * NTPL + i) * 2 + 1] = x1;
    }
}

extern "C" void kernel_launch(void* const* d_in, const int* in_sizes, int n_in,
                              void* d_out, int out_size, void* d_ws, size_t ws_size,
                              hipStream_t stream)
{
    const float* q0  = (const float*)d_in[0];   // [16,64,2]
    const float* tpl = (const float*)d_in[1];   // [2048,2]
    const float* cp  = (const float*)d_in[2];   // [64,2]
    const float* W1  = (const float*)d_in[3];   // [4,10]
    const float* b1  = (const float*)d_in[4];   // [10]
    const float* W2  = (const float*)d_in[5];   // [10,10]
    const float* b2  = (const float*)d_in[6];   // [10]
    const float* W3  = (const float*)d_in[7];   // [10,3]
    const float* b3  = (const float*)d_in[8];   // [3]
    float* out = (float*)d_out;

    float* ws = (float*)d_ws;
    const int slab = BTS * NCP * 2;            // 2048 floats per time slice
    float* p_hist = ws;                        // NFLOW * slab
    float* q_hist = ws + (size_t)NFLOW * slab; // NFLOW * slab

    init_kernel<<<4, 256, 0, stream>>>(q0, cp, p_hist, q_hist);

    for (int s = 0; s < TSTEPS; ++s) {
        shoot_step<<<BTS * NCP, 64, 0, stream>>>(
            p_hist + (size_t)s * slab, q_hist + (size_t)s * slab,
            p_hist + (size_t)(s + 1) * slab, q_hist + (size_t)(s + 1) * slab,
            W1, b1, W2, b2, W3, b3);
    }

    flow_kernel<<<BTS * NTPL, 64, 0, stream>>>(
        tpl, p_hist, q_hist, out, W1, b1, W2, b2, W3, b3);
}

// Round 2
// 408.384 us; speedup vs baseline: 1.1019x; 1.1019x over previous
//
#include <hip/hip_runtime.h>

#define NCP   64
#define BTS   16
#define NTPL  2048
#define TSTEPS 6
#define NFLOW  7           // T+1 stored (p,q) states
#define DTF   0.2f         // 1/(T-1)

// ---------- fast scalar helpers ----------
__device__ __forceinline__ float fast_rcp(float x) {
    return __builtin_amdgcn_rcpf(x);
}
__device__ __forceinline__ float fexp2(float x) {
    return __builtin_amdgcn_exp2f(x);
}
__device__ __forceinline__ float fast_tanh(float x) {
    // tanh(x) = 1 - 2/(1+exp(2x)); exact limits at +/-inf
    float e = __expf(2.0f * x);
    return 1.0f - 2.0f * fast_rcp(1.0f + e);
}

// ---------- tiny MLP forward (original weights; used by shoot) ----------
template <bool STASH>
__device__ __forceinline__ void mlp_fwd(
    float z0, float z1, float z2, float z3,
    const float* __restrict__ W1, const float* __restrict__ b1,
    const float* __restrict__ W2, const float* __restrict__ b2,
    const float* __restrict__ W3, const float* __restrict__ b3,
    float& o0, float& e1, float& e2, float* h1s, float* h2s)
{
    float h1[10];
#pragma unroll
    for (int k = 0; k < 10; ++k) {
        float u = fmaf(z3, W1[30 + k],
                  fmaf(z2, W1[20 + k],
                  fmaf(z1, W1[10 + k],
                  fmaf(z0, W1[k], b1[k]))));
        h1[k] = fast_tanh(u);
        if (STASH) h1s[k] = h1[k];
    }
    float u2[10];
#pragma unroll
    for (int k = 0; k < 10; ++k) u2[k] = b2[k];
#pragma unroll
    for (int c = 0; c < 10; ++c) {
#pragma unroll
        for (int k = 0; k < 10; ++k) u2[k] = fmaf(h1[c], W2[c * 10 + k], u2[k]);
    }
    float o0a = b3[0], o1a = b3[1], o2a = b3[2];
#pragma unroll
    for (int c = 0; c < 10; ++c) {
        float h2 = fast_tanh(u2[c]);
        if (STASH) h2s[c] = h2;
        o0a = fmaf(h2, W3[c * 3 + 0], o0a);
        o1a = fmaf(h2, W3[c * 3 + 1], o1a);
        o2a = fmaf(h2, W3[c * 3 + 2], o2a);
    }
    o0 = o0a;
    e1 = __expf(o1a);
    e2 = __expf(o2a);
}

// ---------- weight transform for the flow kernel ----------
// tanh(u) = 1 - 2*r, r = rcp(1 + exp2(2*log2e*u)). Fold the exp2 scale into
// W1/b1 and (via the affine push-through) W2/b2; fold the (1-2r) affine of
// each layer into the NEXT layer's weights; fold log2e + the 0.5 kernel
// symmetrization factor into W3 columns / b3.
// Layout in wt[]: W1t[40] b1t[10] W2t[100] b2t[10] C0[10] C1[10] C2[10] b3t[3]
__global__ void xform_weights(const float* __restrict__ W1, const float* __restrict__ b1,
                              const float* __restrict__ W2, const float* __restrict__ b2,
                              const float* __restrict__ W3, const float* __restrict__ b3,
                              float* __restrict__ wt)
{
    const float L2 = 1.4426950408889634f;   // log2(e)
    int t = threadIdx.x;
    if (t < 40) wt[t] = 2.0f * L2 * W1[t];
    if (t < 10) wt[40 + t] = 2.0f * L2 * b1[t];
    for (int i = t; i < 100; i += 64) wt[50 + i] = -4.0f * L2 * W2[i];
    if (t < 10) {
        float s = b2[t];
        for (int c = 0; c < 10; ++c) s += W2[c * 10 + t];
        wt[150 + t] = 2.0f * L2 * s;                 // b2''
        wt[160 + t] = -W3[t * 3 + 0];                // C0: 0.5 * (-2 W3[:,0])
        wt[170 + t] = -2.0f * L2 * W3[t * 3 + 1];    // C1
        wt[180 + t] = -2.0f * L2 * W3[t * 3 + 2];    // C2
    }
    if (t < 3) {
        float s = b3[t];
        for (int c = 0; c < 10; ++c) s += W3[c * 3 + t];
        // col0: O0 carries the 0.5 factor; cols1/2: exp2 arg, -1 == *0.5
        wt[190 + t] = (t == 0) ? 0.5f * s : fmaf(L2, s, -1.0f);
    }
}

// ---------- init: p_hist[0] = broadcast(control_points), q_hist[0] = q_0 ----------
__global__ void init_kernel(const float* __restrict__ q0,
                            const float* __restrict__ cp,
                            float* __restrict__ p_hist,
                            float* __restrict__ q_hist)
{
    int t = blockIdx.x * blockDim.x + threadIdx.x;
    if (t < BTS * NCP) {
        int j = t & (NCP - 1);
        p_hist[t * 2 + 0] = cp[j * 2 + 0];
        p_hist[t * 2 + 1] = cp[j * 2 + 1];
        q_hist[t * 2 + 0] = q0[t * 2 + 0];
        q_hist[t * 2 + 1] = q0[t * 2 + 1];
    }
}

// ---------- one symplectic-Euler shooting step ----------
// block = (batch, a) wave; thread = b. (64,1): grid-limited occupancy anyway,
// give the register allocator full budget so the stash arrays don't spill.
__global__ __launch_bounds__(64, 1)
void shoot_step(const float* __restrict__ p_in, const float* __restrict__ q_in,
                float* __restrict__ p_out, float* __restrict__ q_out,
                const float* __restrict__ W1, const float* __restrict__ b1,
                const float* __restrict__ W2, const float* __restrict__ b2,
                const float* __restrict__ W3, const float* __restrict__ b3)
{
    int blk = blockIdx.x;          // 0..BTS*NCP-1
    int batch = blk >> 6;
    int a = blk & (NCP - 1);
    int b = threadIdx.x;

    const float* pB = p_in + batch * NCP * 2;
    const float* qB = q_in + batch * NCP * 2;
    float pax = pB[a * 2 + 0], pay = pB[a * 2 + 1];
    float qax = qB[a * 2 + 0], qay = qB[a * 2 + 1];
    float pbx = pB[b * 2 + 0], pby = pB[b * 2 + 1];
    float qbx = qB[b * 2 + 0], qby = qB[b * 2 + 1];

    float dhq_x = 0.f, dhq_y = 0.f;
    float g_x = 0.f, g_y = 0.f;
    float cross = fmaf(qax, qby, qay * qbx);

#pragma unroll
    for (int e = 0; e < 2; ++e) {
        float z0 = e ? pbx : pax;
        float z1 = e ? pby : pay;
        float z2 = e ? pax : pbx;
        float z3 = e ? pay : pby;

        float h1[10], h2[10];
        float o0, e1, e2;
        mlp_fwd<true>(z0, z1, z2, z3, W1, b1, W2, b2, W3, b3, o0, e1, e2, h1, h2);

        dhq_x = fmaf(0.5f, fmaf(e1, qbx, o0 * qby), dhq_x);
        dhq_y = fmaf(0.5f, fmaf(o0, qbx, e2 * qby), dhq_y);

        float d0 = cross;
        float d1 = e1 * qax * qbx;
        float d2 = e2 * qay * qby;

        float du2[10];
#pragma unroll
        for (int c = 0; c < 10; ++c) {
            float dh2 = fmaf(W3[c * 3 + 0], d0,
                        fmaf(W3[c * 3 + 1], d1, W3[c * 3 + 2] * d2));
            du2[c] = dh2 * (1.0f - h2[c] * h2[c]);
        }
        float du1[10];
#pragma unroll
        for (int c = 0; c < 10; ++c) {
            float dh1 = 0.f;
#pragma unroll
            for (int k = 0; k < 10; ++k) dh1 = fmaf(W2[c * 10 + k], du2[k], dh1);
            du1[c] = dh1 * (1.0f - h1[c] * h1[c]);
        }
        int c0 = e ? 2 : 0;
        float ga = 0.f, gb = 0.f;
#pragma unroll
        for (int k = 0; k < 10; ++k) {
            ga = fmaf(W1[(0 + c0) * 10 + k], du1[k], ga);
            gb = fmaf(W1[(1 + c0) * 10 + k], du1[k], gb);
        }
        g_x = fmaf(0.5f, ga, g_x);
        g_y = fmaf(0.5f, gb, g_y);
    }

#pragma unroll
    for (int off = 32; off > 0; off >>= 1) {
        dhq_x += __shfl_xor(dhq_x, off);
        dhq_y += __shfl_xor(dhq_y, off);
        g_x   += __shfl_xor(g_x, off);
        g_y   += __shfl_xor(g_y, off);
    }

    if (b == 0) {
        float* pO = p_out + (batch * NCP + a) * 2;
        float* qO = q_out + (batch * NCP + a) * 2;
        pO[0] = fmaf(DTF, dhq_x, pax);
        pO[1] = fmaf(DTF, dhq_y, pay);
        qO[0] = fmaf(-DTF, g_x, qax);
        qO[1] = fmaf(-DTF, g_y, qay);
    }
}

// ---------- flow kernel: 4 waves/block, wave = (batch, template point) ----------
__global__ __launch_bounds__(256, 4)
void flow_kernel(const float* __restrict__ tpl,
                 const float* __restrict__ p_hist,   // [NFLOW][BTS][NCP][2]
                 const float* __restrict__ q_hist,
                 float* __restrict__ out,            // [BTS][NTPL][2]
                 const float* __restrict__ wt)
{
    const float* __restrict__ W1t = wt;          // [4][10] scaled
    const float* __restrict__ b1t = wt + 40;
    const float* __restrict__ W2t = wt + 50;     // [10][10]
    const float* __restrict__ b2t = wt + 150;
    const float* __restrict__ C0  = wt + 160;
    const float* __restrict__ C1  = wt + 170;
    const float* __restrict__ C2  = wt + 180;
    const float* __restrict__ b3t = wt + 190;

    int unit = blockIdx.x * 4 + (threadIdx.x >> 6);   // 0..BTS*NTPL-1
    int j = threadIdx.x & 63;
    int batch = unit >> 11;
    int i = unit & (NTPL - 1);

    float x0 = tpl[i * 2 + 0];
    float x1 = tpl[i * 2 + 1];

#pragma unroll
    for (int s = 0; s < NFLOW; ++s) {
        const float* p = p_hist + (((size_t)s * BTS + batch) * NCP + j) * 2;
        const float* q = q_hist + (((size_t)s * BTS + batch) * NCP + j) * 2;
        float pj0 = p[0], pj1 = p[1];
        float qj0 = q[0], qj1 = q[1];

        float vx = 0.f, vy = 0.f;
#pragma unroll
        for (int e = 0; e < 2; ++e) {
            float z0 = e ? pj0 : x0;
            float z1 = e ? pj1 : x1;
            float z2 = e ? x0 : pj0;
            float z3 = e ? x1 : pj1;

            float r1[10];
#pragma unroll
            for (int k = 0; k < 10; ++k) {
                float tt = fmaf(z3, W1t[30 + k],
                           fmaf(z2, W1t[20 + k],
                           fmaf(z1, W1t[10 + k],
                           fmaf(z0, W1t[k], b1t[k]))));
                r1[k] = fast_rcp(1.0f + fexp2(tt));
            }
            float t2[10];
#pragma unroll
            for (int k = 0; k < 10; ++k) t2[k] = b2t[k];
#pragma unroll
            for (int c = 0; c < 10; ++c) {
#pragma unroll
                for (int k = 0; k < 10; ++k) t2[k] = fmaf(r1[c], W2t[c * 10 + k], t2[k]);
            }
            float O0 = b3t[0], T1 = b3t[1], T2 = b3t[2];
#pragma unroll
            for (int c = 0; c < 10; ++c) {
                float r2 = fast_rcp(1.0f + fexp2(t2[c]));
                O0 = fmaf(r2, C0[c], O0);
                T1 = fmaf(r2, C1[c], T1);
                T2 = fmaf(r2, C2[c], T2);
            }
            float E1 = fexp2(T1);   // 0.5*exp(o1) folded
            float E2 = fexp2(T2);
            vx = fmaf(E1, qj0, fmaf(O0, qj1, vx));
            vy = fmaf(O0, qj0, fmaf(E2, qj1, vy));
        }
#pragma unroll
        for (int off = 32; off > 0; off >>= 1) {
            vx += __shfl_xor(vx, off);
            vy += __shfl_xor(vy, off);
        }
        x0 = fmaf(DTF, vx, x0);
        x1 = fmaf(DTF, vy, x1);
    }

    if (j == 0) {
        out[((size_t)batch * NTPL + i) * 2 + 0] = x0;
        out[((size_t)batch * NTPL + i) * 2 + 1] = x1;
    }
}

extern "C" void kernel_launch(void* const* d_in, const int* in_sizes, int n_in,
                              void* d_out, int out_size, void* d_ws, size_t ws_size,
                              hipStream_t stream)
{
    const float* q0  = (const float*)d_in[0];   // [16,64,2]
    const float* tpl = (const float*)d_in[1];   // [2048,2]
    const float* cp  = (const float*)d_in[2];   // [64,2]
    const float* W1  = (const float*)d_in[3];   // [4,10]
    const float* b1  = (const float*)d_in[4];   // [10]
    const float* W2  = (const float*)d_in[5];   // [10,10]
    const float* b2  = (const float*)d_in[6];   // [10]
    const float* W3  = (const float*)d_in[7];   // [10,3]
    const float* b3  = (const float*)d_in[8];   // [3]
    float* out = (float*)d_out;

    float* ws = (float*)d_ws;
    const int slab = BTS * NCP * 2;            // 2048 floats per time slice
    float* p_hist = ws;                        // NFLOW * slab
    float* q_hist = ws + (size_t)NFLOW * slab; // NFLOW * slab
    float* wt     = ws + (size_t)2 * NFLOW * slab;  // 193 floats

    init_kernel<<<4, 256, 0, stream>>>(q0, cp, p_hist, q_hist);
    xform_weights<<<1, 64, 0, stream>>>(W1, b1, W2, b2, W3, b3, wt);

    for (int s = 0; s < TSTEPS; ++s) {
        shoot_step<<<BTS * NCP, 64, 0, stream>>>(
            p_hist + (size_t)s * slab, q_hist + (size_t)s * slab,
            p_hist + (size_t)(s + 1) * slab, q_hist + (size_t)(s + 1) * slab,
            W1, b1, W2, b2, W3, b3);
    }

    flow_kernel<<<BTS * NTPL / 4, 256, 0, stream>>>(
        tpl, p_hist, q_hist, out, wt);
}